// Round 1
// baseline (6049.929 us; speedup 1.0000x reference)
//
#include <hip/hip_runtime.h>

typedef unsigned short u16;
typedef unsigned int u32;
typedef __bf16 bf16x8 __attribute__((ext_vector_type(8)));
typedef float f32x4 __attribute__((ext_vector_type(4)));

#define B_ 1024
#define T_ 128
#define I_ 1024
#define H_ 1024
#define KTOT 2048   // I + H
#define NKT 32      // K-tiles of 64 bf16 cols

__device__ __forceinline__ u16 bf16rne(float f) {
  u32 u = __float_as_uint(f);
  u32 r = (u + 0x7fffu + ((u >> 16) & 1u)) >> 16;
  return (u16)r;
}
__device__ __forceinline__ float bf16tof(u16 s) { return __uint_as_float(((u32)s) << 16); }
__device__ __forceinline__ float sigm(float x) { return 1.0f / (1.0f + __expf(-x)); }
__device__ __forceinline__ float tanh_fast(float x) {
  float e = __expf(2.0f * x);
  return 1.0f - 2.0f / (e + 1.0f);
}

__device__ __forceinline__ void gld_lds16(void* lds, const void* g) {
  __builtin_amdgcn_global_load_lds((const __attribute__((address_space(1))) u32*)g,
                                   (__attribute__((address_space(3))) u32*)lds, 16, 0, 0);
}

// -------------------- init: convert weights / state --------------------
__global__ void k_init(const float* __restrict__ W_ih, const float* __restrict__ W_hh,
                       const float* __restrict__ b_ih, const float* __restrict__ b_hh,
                       const float* __restrict__ h0, const float* __restrict__ c0,
                       const float* __restrict__ inputs,
                       u16* __restrict__ Wcat, float* __restrict__ bias,
                       float* __restrict__ cst,
                       u16* __restrict__ xh_hi0, u16* __restrict__ xh_lo0) {
  const size_t stride = (size_t)gridDim.x * blockDim.x;
  for (size_t i = (size_t)blockIdx.x * blockDim.x + threadIdx.x; i < (size_t)8 * 1024 * 1024; i += stride) {
    const int n = (int)(i >> 11);
    const int k = (int)(i & 2047);
    const float w = (k < I_) ? W_ih[(size_t)n * I_ + k] : W_hh[(size_t)n * H_ + (k - I_)];
    Wcat[i] = bf16rne(w);
    if (i < 4096) bias[i] = b_ih[i] + b_hh[i];
    if (i < (size_t)1024 * 1024) {
      cst[i] = c0[i];
      const int m = (int)(i >> 10);
      const int kk = (int)(i & 1023);
      const float h = h0[i];
      const u16 hh = bf16rne(h);
      const u16 hl = bf16rne(h - bf16tof(hh));
      xh_hi0[(size_t)m * KTOT + H_ + kk] = hh;
      xh_lo0[(size_t)m * KTOT + H_ + kk] = hl;
      const float x = inputs[(size_t)m * T_ * I_ + kk];  // t = 0
      const u16 xh = bf16rne(x);
      const u16 xl = bf16rne(x - bf16tof(xh));
      xh_hi0[(size_t)m * KTOT + kk] = xh;
      xh_lo0[(size_t)m * KTOT + kk] = xl;
    }
  }
}

// -------------------- fused LSTM step --------------------
// block: 256 thr (4 waves). tile: 128 batch rows x 32 j-cols x 4 gates.
// A = [x_t | h_t] hi/lo bf16 [1024][2048]; B = Wcat bf16 [4096][2048].
__global__ __launch_bounds__(256, 1) void lstm_step(
    const u16* __restrict__ Wcat, const float* __restrict__ bias,
    const float* __restrict__ inputs,
    const u16* __restrict__ Ah, const u16* __restrict__ Al,
    u16* __restrict__ Nh, u16* __restrict__ Nl,
    float* __restrict__ cst, int t) {
  const int tid = threadIdx.x;
  const int lane = tid & 63;
  const int wq = tid >> 6;
  const int bid = blockIdx.x;
  const int m0 = (bid & 7) * 128;   // bid%8 -> XCD: keep m-slice resident per XCD
  const int jt = bid >> 3;          // 0..31
  const int j0 = jt * 32;

  __shared__ __align__(16) u16 lds[2][3][128 * 64];  // [buf][Ahi,Alo,B][row*64+col] = 96 KB

  const f32x4 z4 = {0.f, 0.f, 0.f, 0.f};
  f32x4 acc[2][4][2];
#pragma unroll
  for (int a = 0; a < 2; ++a)
#pragma unroll
    for (int g = 0; g < 4; ++g)
#pragma unroll
      for (int n = 0; n < 2; ++n) acc[a][g][n] = z4;

  // stage one K-tile (64 bf16 cols): 3 tiles x 16KB; per wave 4 chunks/tile.
  // LDS dest linear (lane*16); global source pre-swizzled u^(row&7) so that a
  // swizzled ds_read is conflict-free (rule #21 / G4).
  auto stage = [&](int bb, int kt) {
    const int k0 = kt * 64;
#pragma unroll
    for (int cc2 = 0; cc2 < 4; ++cc2) {
      const int ch = wq * 4 + cc2;          // chunk 0..15
      const int r = ch * 8 + (lane >> 3);   // tile row 0..127
      const int us = (lane & 7) ^ (r & 7);  // swizzled 16B unit
      const int dst = ch * 512 + lane * 8;  // u16 index; = lane*16B within chunk
      gld_lds16(&lds[bb][0][dst], Ah + (size_t)(m0 + r) * KTOT + k0 + us * 8);
      gld_lds16(&lds[bb][1][dst], Al + (size_t)(m0 + r) * KTOT + k0 + us * 8);
      const int n = ((r >> 5) << 10) + j0 + (r & 31);  // gate row
      gld_lds16(&lds[bb][2][dst], Wcat + (size_t)n * KTOT + k0 + us * 8);
    }
  };

  stage(0, 0);
#pragma unroll 1
  for (int kt = 0; kt < NKT; ++kt) {
    const int cb = kt & 1;
    if (kt + 1 < NKT) {
      stage(cb ^ 1, kt + 1);
      // 12 new loads in flight; wait for the 12 older (current tile) only.
      asm volatile("s_waitcnt vmcnt(12)\n\ts_barrier" ::: "memory");
    } else {
      asm volatile("s_waitcnt vmcnt(0)\n\ts_barrier" ::: "memory");
    }

    const int r15 = lane & 15;
    const int q = lane >> 4;
#pragma unroll
    for (int ks = 0; ks < 2; ++ks) {
      bf16x8 ah[2], al[2];
#pragma unroll
      for (int mi = 0; mi < 2; ++mi) {
        const int row = wq * 32 + mi * 16 + r15;
        const int u = (((ks << 2) + q) ^ (row & 7)) << 3;
        ah[mi] = *(const bf16x8*)&lds[cb][0][row * 64 + u];
        al[mi] = *(const bf16x8*)&lds[cb][1][row * 64 + u];
      }
      bf16x8 bfr[4][2];
#pragma unroll
      for (int g = 0; g < 4; ++g)
#pragma unroll
        for (int ni = 0; ni < 2; ++ni) {
          const int row = g * 32 + ni * 16 + r15;
          const int u = (((ks << 2) + q) ^ (row & 7)) << 3;
          bfr[g][ni] = *(const bf16x8*)&lds[cb][2][row * 64 + u];
        }
#pragma unroll
      for (int mi = 0; mi < 2; ++mi)
#pragma unroll
        for (int g = 0; g < 4; ++g)
#pragma unroll
          for (int ni = 0; ni < 2; ++ni) {
            acc[mi][g][ni] = __builtin_amdgcn_mfma_f32_16x16x32_bf16(ah[mi], bfr[g][ni], acc[mi][g][ni], 0, 0, 0);
            acc[mi][g][ni] = __builtin_amdgcn_mfma_f32_16x16x32_bf16(al[mi], bfr[g][ni], acc[mi][g][ni], 0, 0, 0);
          }
    }
    asm volatile("s_barrier" ::: "memory");
  }

  // ---- epilogue: all 4 gates in-lane -> c/h update ----
  const int r15 = lane & 15;
  const int q4 = (lane >> 4) * 4;
  float bofs[4][2];
#pragma unroll
  for (int g = 0; g < 4; ++g)
#pragma unroll
    for (int ni = 0; ni < 2; ++ni) bofs[g][ni] = bias[(g << 10) + j0 + ni * 16 + r15];

#pragma unroll
  for (int mi = 0; mi < 2; ++mi)
#pragma unroll
    for (int ni = 0; ni < 2; ++ni) {
      const int j = j0 + ni * 16 + r15;
#pragma unroll
      for (int r = 0; r < 4; ++r) {
        const int m = m0 + wq * 32 + mi * 16 + q4 + r;
        const float vi = acc[mi][0][ni][r] + bofs[0][ni];
        const float vf = acc[mi][1][ni][r] + bofs[1][ni];
        const float vg = acc[mi][2][ni][r] + bofs[2][ni];
        const float vo = acc[mi][3][ni][r] + bofs[3][ni];
        const float ig = sigm(vi) * tanh_fast(vg);
        const float ff = sigm(vf);
        const float oo = sigm(vo);
        const size_t ci = (size_t)m * H_ + j;
        const float cn = ff * cst[ci] + ig;
        cst[ci] = cn;
        const float h = oo * tanh_fast(cn);
        const u16 hh = bf16rne(h);
        const u16 hl = bf16rne(h - bf16tof(hh));
        Nh[(size_t)m * KTOT + H_ + j] = hh;
        Nl[(size_t)m * KTOT + H_ + j] = hl;
      }
    }

  // ---- tail: convert x_{t+1} into next buffer (hidden behind this step) ----
  if (t + 1 < T_) {
    const int row8 = tid >> 5;   // 0..7
    const int col = tid & 31;
#pragma unroll 1
    for (int p = 0; p < 16; ++p) {
      const int m = m0 + p * 8 + row8;
      const float x = inputs[((size_t)m * T_ + (t + 1)) * I_ + j0 + col];
      const u16 xh = bf16rne(x);
      const u16 xl = bf16rne(x - bf16tof(xh));
      Nh[(size_t)m * KTOT + j0 + col] = xh;
      Nl[(size_t)m * KTOT + j0 + col] = xl;
    }
  }
}

// -------------------- output head: y = h_T @ W_out^T + b_out --------------------
__global__ __launch_bounds__(64) void k_out(const u16* __restrict__ xh_hi0, const u16* __restrict__ xh_lo0,
                                            const float* __restrict__ W_out, const float* __restrict__ b_out,
                                            float* __restrict__ out) {
  const int m = blockIdx.x;
  const int lane = threadIdx.x;
  float h[16];
#pragma unroll
  for (int i = 0; i < 16; ++i) {
    const int k = lane + i * 64;
    h[i] = bf16tof(xh_hi0[(size_t)m * KTOT + H_ + k]) + bf16tof(xh_lo0[(size_t)m * KTOT + H_ + k]);
  }
  for (int cc = 0; cc < 10; ++cc) {
    float s = 0.f;
#pragma unroll
    for (int i = 0; i < 16; ++i) s += h[i] * W_out[(size_t)cc * H_ + lane + i * 64];
    for (int off = 32; off > 0; off >>= 1) s += __shfl_down(s, off, 64);
    if (lane == 0) out[m * 10 + cc] = s + b_out[cc];
  }
}

extern "C" void kernel_launch(void* const* d_in, const int* in_sizes, int n_in,
                              void* d_out, int out_size, void* d_ws, size_t ws_size,
                              hipStream_t stream) {
  (void)in_sizes; (void)n_in; (void)out_size; (void)ws_size;
  const float* inputs = (const float*)d_in[0];
  const float* h0    = (const float*)d_in[1];
  const float* c0    = (const float*)d_in[2];
  const float* W_ih  = (const float*)d_in[3];
  const float* b_ih  = (const float*)d_in[4];
  const float* W_hh  = (const float*)d_in[5];
  const float* b_hh  = (const float*)d_in[6];
  const float* W_out = (const float*)d_in[7];
  const float* b_out = (const float*)d_in[8];

  char* ws = (char*)d_ws;
  const size_t M = 1024ull * 1024ull;
  u16*  Wcat = (u16*)(ws);                 // 16 MB  bf16 [4096][2048]
  float* bias = (float*)(ws + 16 * M);     // 16 KB
  float* cst  = (float*)(ws + 17 * M);     // 4 MB fp32 [1024][1024]
  u16* xh_hi[2] = { (u16*)(ws + 21 * M), (u16*)(ws + 25 * M) };  // 4 MB each [1024][2048]
  u16* xh_lo[2] = { (u16*)(ws + 29 * M), (u16*)(ws + 33 * M) };  // 4 MB each

  k_init<<<2048, 256, 0, stream>>>(W_ih, W_hh, b_ih, b_hh, h0, c0, inputs,
                                   Wcat, bias, cst, xh_hi[0], xh_lo[0]);
  for (int t = 0; t < T_; ++t) {
    const int cur = t & 1;
    lstm_step<<<256, 256, 0, stream>>>(Wcat, bias, inputs,
                                       xh_hi[cur], xh_lo[cur],
                                       xh_hi[cur ^ 1], xh_lo[cur ^ 1],
                                       cst, t);
  }
  k_out<<<1024, 64, 0, stream>>>(xh_hi[0], xh_lo[0], W_out, b_out, (float*)d_out);
}